// Round 3
// baseline (63.323 us; speedup 1.0000x reference)
//
#include <hip/hip_runtime.h>
#include <hip/hip_bf16.h>

// Rasterize_51908974739476 — soft rasterizer forward on MI355X.
// Dtype model (evidence across rounds 0-2):
//   R0: zero-buffer fim err == 512.0 exactly  => ref compared after bf16
//       rounding (bf16-flavor tolerances), not buffer dtype proof.
//   R1: feature err 2.2e37 with weights provably in [0,1]  => inputs are f32
//       storage (bf16 reinterpret gave garbage-exponent textures).
//   R2: feature err 516.6016: my bf16 fim writes (<=0x4400=512) at element
//       663552 land at f32 index 331776 inside the feature chunk; f32 word
//       with high half 0x4400 decodes to [512,516) vs ref +-4.2 => 516.6.
//       => OUTPUT buffer is f32 storage as well.
//   d_in[0] = faces    f32 (B,F,3,3)  = 9216
//   d_in[1] = textures f32 (B,F,3,T)  = 24576
//   d_out   = f32 concat feature(2,9,192,192) | fim(2,192,192) | dmap(2,192,192)
// All math in f32; det/w0/w1/w2 replicate numpy's expression order with
// fp-contract OFF so inside-test signs match the reference bitwise.

namespace {
constexpr int BB = 2, FF = 512, HH = 192, WW = 192, TT = 8;
constexpr int TILE = 16;
constexpr int HWSZ = HH * WW;
constexpr float NEARF = 0.5f, FARF = 100.0f, EPSF = 1e-8f;
}

__global__ __launch_bounds__(256) void raster_fused_kernel(
    const float* __restrict__ faces,
    const float* __restrict__ textures,
    float* __restrict__ out)
{
#pragma clang fp contract(off)
  __shared__ float sx0[FF], sy0[FF], sx1[FF], sy1[FF], sx2[FF], sy2[FF];
  __shared__ float siz0[FF], siz1[FF], siz2[FF], sinv[FF];
  __shared__ int s_count;
  __shared__ unsigned short s_list[FF];

  const int tx = threadIdx.x, ty = threadIdx.y;
  const int tid = ty * TILE + tx;
  const int bx = blockIdx.x, by = blockIdx.y, b = blockIdx.z;

  if (tid == 0) s_count = 0;
  __syncthreads();

  // Tile pixel-center bounds in NDC (same formula as reference px/py)
  const float px_lo = (2.0f * ((float)(bx * TILE) + 0.5f) - (float)WW) / (float)WW;
  const float px_hi = (2.0f * ((float)(bx * TILE + TILE - 1) + 0.5f) - (float)WW) / (float)WW;
  const float py_lo = (2.0f * ((float)(by * TILE) + 0.5f) - (float)HH) / (float)HH;
  const float py_hi = (2.0f * ((float)(by * TILE + TILE - 1) + 0.5f) - (float)HH) / (float)HH;

  // Stage all faces into LDS; bbox-cull & compact survivors for this tile.
  for (int f = tid; f < FF; f += 256) {
    const float* fp = faces + (size_t)(b * FF + f) * 9;
    float x0 = fp[0], y0 = fp[1], z0 = fp[2];
    float x1 = fp[3], y1 = fp[4], z1 = fp[5];
    float x2 = fp[6], y2 = fp[7], z2 = fp[8];
    // det exactly as reference (contract off => bitwise-match numpy f32)
    float det = (x1 - x0) * (y2 - y0) - (x2 - x0) * (y1 - y0);
    bool ok = fabsf(det) > EPSF;
    float invdet = 1.0f / (ok ? det : 1.0f);
    sx0[f] = x0; sy0[f] = y0;
    sx1[f] = x1; sy1[f] = y1;
    sx2[f] = x2; sy2[f] = y2;
    siz0[f] = 1.0f / z0; siz1[f] = 1.0f / z1; siz2[f] = 1.0f / z2;
    sinv[f] = invdet;
    if (ok) {
      float xmn = fminf(x0, fminf(x1, x2)), xmx = fmaxf(x0, fmaxf(x1, x2));
      float ymn = fminf(y0, fminf(y1, y2)), ymx = fmaxf(y0, fmaxf(y1, y2));
      // inside => pixel center lies in the face's closed bbox => cull is exact
      if (xmx >= px_lo && xmn <= px_hi && ymx >= py_lo && ymn <= py_hi) {
        int slot = atomicAdd(&s_count, 1);
        s_list[slot] = (unsigned short)f;
      }
    }
  }
  __syncthreads();

  const int w = bx * TILE + tx;
  const int h = by * TILE + ty;
  const float px = (2.0f * ((float)w + 0.5f) - (float)WW) / (float)WW;
  const float py = (2.0f * ((float)h + 0.5f) - (float)HH) / (float)HH;

  float best = FARF;
  int bestf = 0;
  float bw0 = 0.0f, bw1 = 0.0f, bw2 = 0.0f;
  const int cnt = s_count;
  for (int i = 0; i < cnt; ++i) {
    const int f = s_list[i];
    // Replicate reference expression order exactly (contract off).
    float dx0 = sx0[f] - px, dy0 = sy0[f] - py;
    float dx1 = sx1[f] - px, dy1 = sy1[f] - py;
    float dx2 = sx2[f] - px, dy2 = sy2[f] - py;
    float invdet = sinv[f];
    float w0 = (dx1 * dy2 - dx2 * dy1) * invdet;
    float w1 = (dx2 * dy0 - dx0 * dy2) * invdet;
    float w2 = 1.0f - w0 - w1;
    if (w0 >= 0.0f && w1 >= 0.0f && w2 >= 0.0f) {
      // 1/z precomputed: <=1ulp vs ref's w/z — cannot flip argmin on
      // continuous data; dmap tolerance is huge vs that.
      float invd = w0 * siz0[f] + w1 * siz1[f] + w2 * siz2[f];
      if (invd > EPSF) {
        float d = 1.0f / invd;
        if (d >= NEARF && d <= FARF && d < best) {  // strict < == argmin-first
          best = d; bestf = f;
          bw0 = w0; bw1 = w1; bw2 = w2;
        }
      }
    }
  }

  const bool covered = best < FARF;
  const size_t pix = (size_t)h * WW + w;
  float* featp = out + (size_t)b * 9 * HWSZ + pix;
  if (covered) {
    const float* tp = textures + (size_t)(b * FF + bestf) * 3 * TT;
    #pragma unroll
    for (int t = 0; t < TT; ++t) {
      float v0 = tp[t];
      float v1 = tp[TT + t];
      float v2 = tp[2 * TT + t];
      float v = bw0 * v0 + bw1 * v1;  // einsum k-order, contract off
      v = v + bw2 * v2;
      featp[(size_t)t * HWSZ] = v;
    }
    featp[(size_t)TT * HWSZ] = 1.0f;  // mask channel
  } else {
    #pragma unroll
    for (int t = 0; t < TT + 1; ++t) featp[(size_t)t * HWSZ] = 0.0f;
  }

  const size_t fim_base = (size_t)BB * 9 * HWSZ;              // 663552
  const size_t dmap_base = fim_base + (size_t)BB * HWSZ;      // 737280
  out[fim_base + (size_t)b * HWSZ + pix] = covered ? (float)bestf : -1.0f;
  out[dmap_base + (size_t)b * HWSZ + pix] = best;  // FAR if uncovered
}

extern "C" void kernel_launch(void* const* d_in, const int* in_sizes, int n_in,
                              void* d_out, int out_size, void* d_ws, size_t ws_size,
                              hipStream_t stream) {
  const float* faces = (const float*)d_in[0];
  const float* textures = (const float*)d_in[1];
  float* out = (float*)d_out;
  dim3 grid(WW / TILE, HH / TILE, BB);  // 12 x 12 x 2
  dim3 block(TILE, TILE, 1);            // 256 threads
  hipLaunchKernelGGL(raster_fused_kernel, grid, block, 0, stream,
                     faces, textures, out);
}

// Round 4
// 62.650 us; speedup vs baseline: 1.0107x; 1.0107x over previous
//
#include <hip/hip_runtime.h>
#include <hip/hip_bf16.h>

// Rasterize_51908974739476 — soft rasterizer forward on MI355X.
// Dtypes (established R0-R2): faces f32 (2,512,3,3), textures f32 (2,512,3,8),
// out f32 concat feature(2,9,192,192) | fim(2,192,192) | dmap(2,192,192);
// comparison is bf16-toleranced. det/w0/w1/w2 replicate numpy's f32
// expression order with fp-contract OFF so inside/argmin decisions match
// the reference bitwise.
//
// R3 -> R4 deltas: (1) coalesced float4 global->LDS staging of raw face data,
// (2) packed 48B per-face LDS records so the pixel loop does 3 vector LDS
// reads/face instead of 10 scalar, (3) unroll-by-2 prefetch for ILP (only
// ~1.1 waves/SIMD resident -> latency must be hidden by ILP), (4) float4
// texture gather in the epilogue.

namespace {
constexpr int BB = 2, FF = 512, HH = 192, WW = 192, TT = 8;
constexpr int TILE = 16;
constexpr int HWSZ = HH * WW;
constexpr int RAW = FF * 9;  // 4608 floats of face data per batch
constexpr float NEARF = 0.5f, FARF = 100.0f, EPSF = 1e-8f;
}

__global__ __launch_bounds__(256) void raster_fused_kernel(
    const float* __restrict__ faces,
    const float* __restrict__ textures,
    float* __restrict__ out)
{
#pragma clang fp contract(off)
  __shared__ float sraw[RAW];        // 18 KB raw face staging (coalesced fill)
  __shared__ float sface[FF * 12];   // 24 KB packed records: x0 y0 x1 y1 | x2 y2 invdet iz0 | iz1 iz2 pad pad
  __shared__ int s_count;
  __shared__ unsigned short s_list[FF];

  const int tx = threadIdx.x, ty = threadIdx.y;
  const int tid = ty * TILE + tx;
  const int bx = blockIdx.x, by = blockIdx.y, b = blockIdx.z;

  if (tid == 0) s_count = 0;

  // --- coalesced raw staging: 1152 float4s, 256 threads, 4.5 rounds ---
  {
    const float4* src = (const float4*)(faces + (size_t)b * RAW);  // 18432B, 16B-aligned
    float4* dst = (float4*)sraw;
    for (int i = tid; i < RAW / 4; i += 256) dst[i] = src[i];
  }
  __syncthreads();

  // Tile pixel-center bounds in NDC (same formula as reference px/py)
  const float px_lo = (2.0f * ((float)(bx * TILE) + 0.5f) - (float)WW) / (float)WW;
  const float px_hi = (2.0f * ((float)(bx * TILE + TILE - 1) + 0.5f) - (float)WW) / (float)WW;
  const float py_lo = (2.0f * ((float)(by * TILE) + 0.5f) - (float)HH) / (float)HH;
  const float py_hi = (2.0f * ((float)(by * TILE + TILE - 1) + 0.5f) - (float)HH) / (float)HH;

  // --- derive per-face constants + bbox-cull & compact (stride-9 LDS reads:
  // 9 coprime to 32 banks -> conflict-free) ---
  for (int f = tid; f < FF; f += 256) {
    const float* fp = sraw + f * 9;
    float x0 = fp[0], y0 = fp[1], z0 = fp[2];
    float x1 = fp[3], y1 = fp[4], z1 = fp[5];
    float x2 = fp[6], y2 = fp[7], z2 = fp[8];
    float det = (x1 - x0) * (y2 - y0) - (x2 - x0) * (y1 - y0);  // exact ref order
    bool ok = fabsf(det) > EPSF;
    float invdet = 1.0f / (ok ? det : 1.0f);
    float* dst = sface + f * 12;
    dst[0] = x0; dst[1] = y0; dst[2] = x1; dst[3] = y1;
    dst[4] = x2; dst[5] = y2; dst[6] = invdet; dst[7] = 1.0f / z0;
    dst[8] = 1.0f / z1; dst[9] = 1.0f / z2;
    if (ok) {
      float xmn = fminf(x0, fminf(x1, x2)), xmx = fmaxf(x0, fmaxf(x1, x2));
      float ymn = fminf(y0, fminf(y1, y2)), ymx = fmaxf(y0, fmaxf(y1, y2));
      // inside => pixel center within closed bbox => cull is exact
      if (xmx >= px_lo && xmn <= px_hi && ymx >= py_lo && ymn <= py_hi) {
        int slot = atomicAdd(&s_count, 1);
        s_list[slot] = (unsigned short)f;
      }
    }
  }
  __syncthreads();

  const int w = bx * TILE + tx;
  const int h = by * TILE + ty;
  const float px = (2.0f * ((float)w + 0.5f) - (float)WW) / (float)WW;
  const float py = (2.0f * ((float)h + 0.5f) - (float)HH) / (float)HH;

  float best = FARF;
  int bestf = 0;
  float bw0 = 0.0f, bw1 = 0.0f, bw2 = 0.0f;
  const int cnt = s_count;

  if (cnt > 0) {
    // prefetch face 0 (broadcast vector LDS reads)
    int fnext = s_list[0];
    float4 r0 = *(const float4*)(sface + fnext * 12);
    float4 r1 = *(const float4*)(sface + fnext * 12 + 4);
    float2 r2 = *(const float2*)(sface + fnext * 12 + 8);
    for (int i = 0; i < cnt; ++i) {
      const float4 c0 = r0; const float4 c1 = r1; const float2 c2 = r2;
      const int fcur = fnext;
      if (i + 1 < cnt) {  // prefetch next face while computing current
        fnext = s_list[i + 1];
        r0 = *(const float4*)(sface + fnext * 12);
        r1 = *(const float4*)(sface + fnext * 12 + 4);
        r2 = *(const float2*)(sface + fnext * 12 + 8);
      }
      // c0 = {x0,y0,x1,y1}  c1 = {x2,y2,invdet,iz0}  c2 = {iz1,iz2}
      // Replicate reference expression order exactly (contract off).
      float dx0 = c0.x - px, dy0 = c0.y - py;
      float dx1 = c0.z - px, dy1 = c0.w - py;
      float dx2 = c1.x - px, dy2 = c1.y - py;
      float w0 = (dx1 * dy2 - dx2 * dy1) * c1.z;
      float w1 = (dx2 * dy0 - dx0 * dy2) * c1.z;
      float w2 = 1.0f - w0 - w1;
      if (w0 >= 0.0f && w1 >= 0.0f && w2 >= 0.0f) {
        // 1/z precomputed: <=1ulp vs ref's w/z — cannot flip argmin on
        // continuous data; dmap tolerance is huge vs that.
        float invd = w0 * c1.w + w1 * c2.x + w2 * c2.y;
        if (invd > EPSF) {
          float d = 1.0f / invd;
          if (d >= NEARF && d <= FARF && d < best) {  // strict < == argmin-first
            best = d; bestf = fcur;
            bw0 = w0; bw1 = w1; bw2 = w2;
          }
        }
      }
    }
  }

  const bool covered = best < FARF;
  const size_t pix = (size_t)h * WW + w;
  float* featp = out + (size_t)b * 9 * HWSZ + pix;
  if (covered) {
    const float4* tp = (const float4*)(textures + (size_t)(b * FF + bestf) * 3 * TT);  // 96B rec, 16B-aligned
    float4 t0 = tp[0], t1 = tp[1];  // vertex 0, channels 0..7
    float4 t2 = tp[2], t3 = tp[3];  // vertex 1
    float4 t4 = tp[4], t5 = tp[5];  // vertex 2
    const float* v0 = (const float*)&t0;  // t0,t1 contiguous? use arrays instead
    float a0[8] = {t0.x, t0.y, t0.z, t0.w, t1.x, t1.y, t1.z, t1.w};
    float a1[8] = {t2.x, t2.y, t2.z, t2.w, t3.x, t3.y, t3.z, t3.w};
    float a2[8] = {t4.x, t4.y, t4.z, t4.w, t5.x, t5.y, t5.z, t5.w};
    (void)v0;
    #pragma unroll
    for (int t = 0; t < TT; ++t) {
      float v = bw0 * a0[t] + bw1 * a1[t];  // einsum k-order, contract off
      v = v + bw2 * a2[t];
      featp[(size_t)t * HWSZ] = v;
    }
    featp[(size_t)TT * HWSZ] = 1.0f;  // mask channel
  } else {
    #pragma unroll
    for (int t = 0; t < TT + 1; ++t) featp[(size_t)t * HWSZ] = 0.0f;
  }

  const size_t fim_base = (size_t)BB * 9 * HWSZ;              // 663552
  const size_t dmap_base = fim_base + (size_t)BB * HWSZ;      // 737280
  out[fim_base + (size_t)b * HWSZ + pix] = covered ? (float)bestf : -1.0f;
  out[dmap_base + (size_t)b * HWSZ + pix] = best;  // FAR if uncovered
}

extern "C" void kernel_launch(void* const* d_in, const int* in_sizes, int n_in,
                              void* d_out, int out_size, void* d_ws, size_t ws_size,
                              hipStream_t stream) {
  const float* faces = (const float*)d_in[0];
  const float* textures = (const float*)d_in[1];
  float* out = (float*)d_out;
  dim3 grid(WW / TILE, HH / TILE, BB);  // 12 x 12 x 2
  dim3 block(TILE, TILE, 1);            // 256 threads
  hipLaunchKernelGGL(raster_fused_kernel, grid, block, 0, stream,
                     faces, textures, out);
}